// Round 8
// baseline (93.415 us; speedup 1.0000x reference)
//
#include <hip/hip_runtime.h>
#include <math.h>

#define N_SQ 64
#define TRUNCF 0.1f
#define EPSF 1e-6f
#define PTS_PER_BLOCK 128   // 256 threads: waves 0-1 -> j half 0, waves 2-3 -> j half 1

// --- fast hardware transcendentals (bases are guaranteed > 0 where used) ---
__device__ __forceinline__ float flog2(float x) { return __builtin_amdgcn_logf(x); }   // v_log_f32
__device__ __forceinline__ float fexp2(float x) { return __builtin_amdgcn_exp2f(x); }  // v_exp_f32
__device__ __forceinline__ float frcp(float x)  { return __builtin_amdgcn_rcpf(x); }   // v_rcp_f32
__device__ __forceinline__ float frsq(float x)  { return __builtin_amdgcn_rsqf(x); }   // v_rsq_f32

// Derived per-SQ parameter block: 5 x float4 (80 B), written to d_ws by prep_kernel.
//  [0] = R00,R01,R02,d0    d = -R^T t  (translation folded into the rotate fma)
//  [1] = R10,R11,R12,d1
//  [2] = R20,R21,R22,d2
//  [3] = iSx,iSy,iSz,c2e2  (c2e2 = 2/e2)
//  [4] = c2e1, mm, nh, 0   (c2e1 = 2/e1, mm = e2/e1, nh = -e1/2)
__global__ __launch_bounds__(64) void prep_kernel(
    const float* __restrict__ raw_scale,
    const float* __restrict__ raw_exp,
    const float* __restrict__ raw_rot,
    const float* __restrict__ trans,
    float4* __restrict__ params)
{
    const int j = threadIdx.x;
    if (j >= N_SQ) return;
    float qw = raw_rot[j * 4 + 0], qx = raw_rot[j * 4 + 1];
    float qy = raw_rot[j * 4 + 2], qz = raw_rot[j * 4 + 3];
    const float qn = sqrtf(qw * qw + qx * qx + qy * qy + qz * qz);
    qw /= qn; qx /= qn; qy /= qn; qz /= qn;
    const float e1 = 1.f / (1.f + expf(-raw_exp[j * 2 + 0])) * 1.8f + 0.1f;
    const float e2 = 1.f / (1.f + expf(-raw_exp[j * 2 + 1])) * 1.8f + 0.1f;
    const float R00 = 1.f - 2.f * (qy * qy + qz * qz);
    const float R01 = 2.f * (qx * qy - qw * qz);
    const float R02 = 2.f * (qx * qz + qw * qy);
    const float R10 = 2.f * (qx * qy + qw * qz);
    const float R11 = 1.f - 2.f * (qx * qx + qz * qz);
    const float R12 = 2.f * (qy * qz - qw * qx);
    const float R20 = 2.f * (qx * qz - qw * qy);
    const float R21 = 2.f * (qy * qz + qw * qx);
    const float R22 = 1.f - 2.f * (qx * qx + qy * qy);
    const float T0 = trans[j * 3 + 0];
    const float T1 = trans[j * 3 + 1];
    const float T2 = trans[j * 3 + 2];
    // d = -R^T t  (column k of R dotted with t)
    const float d0 = -(R00 * T0 + R10 * T1 + R20 * T2);
    const float d1 = -(R01 * T0 + R11 * T1 + R21 * T2);
    const float d2 = -(R02 * T0 + R12 * T1 + R22 * T2);
    params[j * 5 + 0] = make_float4(R00, R01, R02, d0);
    params[j * 5 + 1] = make_float4(R10, R11, R12, d1);
    params[j * 5 + 2] = make_float4(R20, R21, R22, d2);
    params[j * 5 + 3] = make_float4(expf(-raw_scale[j * 3 + 0]),
                                    expf(-raw_scale[j * 3 + 1]),
                                    expf(-raw_scale[j * 3 + 2]),
                                    2.f / e2);
    params[j * 5 + 4] = make_float4(2.f / e1, e2 / e1, -e1 * 0.5f, 0.f);
}

// Pass-2: full gradient + normalize + store for one winning SQ.
__device__ __forceinline__ void write_winner(
    const float4* __restrict__ params,
    float px, float py, float pz, int jb, float best,
    float* __restrict__ out_sdf, float* __restrict__ out_nrm, int p)
{
    const float4 r0v = params[jb * 5 + 0];
    const float4 r1v = params[jb * 5 + 1];
    const float4 r2v = params[jb * 5 + 2];
    const float4 sc  = params[jb * 5 + 3];
    const float4 ex  = params[jb * 5 + 4];

    // X = R^T p + d (translation pre-folded)
    const float X0 = r0v.x * px + r1v.x * py + r2v.x * pz + r0v.w;
    const float X1 = r0v.y * px + r1v.y * py + r2v.y * pz + r1v.w;
    const float X2 = r0v.z * px + r1v.z * py + r2v.z * pz + r2v.w;

    const float a0 = fabsf(X0), a1 = fabsf(X1), a2 = fabsf(X2);
    const float ax = fmaxf(a0, EPSF);
    const float ay = fmaxf(a1, EPSF);
    const float az = fmaxf(a2, EPSF);
    const float sm0 = (a0 > EPSF) ? ((X0 > 0.f) ? 1.f : -1.f) : 0.f;
    const float sm1 = (a1 > EPSF) ? ((X1 > 0.f) ? 1.f : -1.f) : 0.f;
    const float sm2 = (a2 > EPSF) ? ((X2 > 0.f) ? 1.f : -1.f) : 0.f;

    const float r2 = ax * ax + ay * ay + az * az;
    const float inv_r0 = frsq(r2);
    const float r0 = r2 * inv_r0;

    const float t1 = fexp2(sc.w * flog2(ax * sc.x));
    const float t2 = fexp2(sc.w * flog2(ay * sc.y));
    const float t3 = fexp2(ex.x * flog2(az * sc.z));

    const float A = t1 + t2 + EPSF;
    const float B = fexp2(ex.y * flog2(A));
    const float S = B + t3;
    const float f = fexp2(ex.z * flog2(S));

    const float omf = 1.f - f;
    const float c1  = omf * inv_r0;
    const float w   = r0 * f * frcp(S);
    const float wBA = w * B * frcp(A);

    const float gmx = fmaf(wBA * t1, frcp(ax), c1 * ax);
    const float gmy = fmaf(wBA * t2, frcp(ay), c1 * ay);
    const float gmz = fmaf(w  * t3, frcp(az), c1 * az);
    const float gx = gmx * sm0;
    const float gy = gmy * sm1;
    const float gz = gmz * sm2;
    const float gpx = r0v.x * gx + r0v.y * gy + r0v.z * gz;
    const float gpy = r1v.x * gx + r1v.y * gy + r1v.z * gz;
    const float gpz = r2v.x * gx + r2v.y * gy + r2v.z * gz;

    const float n2 = gpx * gpx + gpy * gpy + gpz * gpz;
    const float inv_n = frsq(fmaxf(n2, 1e-24f));   // == 1/max(||g||,1e-12)

    out_sdf[p] = best;
    out_nrm[p * 3 + 0] = gpx * inv_n;
    out_nrm[p * 3 + 1] = gpy * inv_n;
    out_nrm[p * 3 + 2] = gpz * inv_n;
}

// sdf-only evaluation (translation pre-folded into d).
__device__ __forceinline__ float sdf_eval(
    const float4& r0v, const float4& r1v, const float4& r2v,
    const float4& sc, const float4& ex,
    float px, float py, float pz)
{
    const float X0 = r0v.x * px + r1v.x * py + r2v.x * pz + r0v.w;
    const float X1 = r0v.y * px + r1v.y * py + r2v.y * pz + r1v.w;
    const float X2 = r0v.z * px + r1v.z * py + r2v.z * pz + r2v.w;

    const float ax = fmaxf(fabsf(X0), EPSF);
    const float ay = fmaxf(fabsf(X1), EPSF);
    const float az = fmaxf(fabsf(X2), EPSF);

    const float r2 = ax * ax + ay * ay + az * az;
    const float inv_r0 = frsq(r2);
    const float r0 = r2 * inv_r0;

    const float t1 = fexp2(sc.w * flog2(ax * sc.x));
    const float t2 = fexp2(sc.w * flog2(ay * sc.y));
    const float t3 = fexp2(ex.x * flog2(az * sc.z));

    const float A = t1 + t2 + EPSF;
    const float B = fexp2(ex.y * flog2(A));
    const float S = B + t3;
    const float f = fexp2(ex.z * flog2(S));

    return fminf(fmaxf(r0 * (1.f - f), -TRUNCF), TRUNCF);
}

// R6 structure (best measured) + hand software-pipelined scalar param loads
// (prefetch distance 2 iterations) to hide s_load lgkmcnt latency — the
// occupancy-invariant ~90 cy/iter stall seen in R2..R7.
__global__ __launch_bounds__(256, 8) void superq_main(
    const float4* __restrict__ params,
    const float* __restrict__ points,
    float* __restrict__ out_sdf,
    float* __restrict__ out_nrm,
    int n_pts)
{
    __shared__ float sBest[256];
    __shared__ int   sJb[256];

    const int tid  = threadIdx.x;
    const int lid  = tid & (PTS_PER_BLOCK - 1);          // local point id 0..127
    const int half = tid >> 7;                           // 0 or 1 (wave-uniform)
    const int p    = blockIdx.x * PTS_PER_BLOCK + lid;
    const bool valid = p < n_pts;

    float px = 0.f, py = 0.f, pz = 0.f;
    if (valid) {
        px = points[p * 3 + 0];
        py = points[p * 3 + 1];
        pz = points[p * 3 + 2];
    }

    // Wave-uniform j base in an SGPR (R5 lesson: tid-derived -> "divergent"
    // -> params would fall off the scalar-load path).
    const int j0 = __builtin_amdgcn_readfirstlane(half * (N_SQ / 2));
    const float4* __restrict__ Pb = params + j0 * 5;

    float best = INFINITY;
    int jb = j0;

    // Software pipeline: evaluate pair (jj, jj+1) while params for
    // (jj+2, jj+3) are in flight. Prefetch overruns read <=5280 B into the
    // (huge) workspace — harmless, values unused.
    float4 c00 = Pb[0], c01 = Pb[1], c02 = Pb[2], c03 = Pb[3], c04 = Pb[4];
    float4 c10 = Pb[5], c11 = Pb[6], c12 = Pb[7], c13 = Pb[8], c14 = Pb[9];

    for (int jj = 0; jj < N_SQ / 2; jj += 2) {
        // issue next pair's loads first (results consumed next iteration)
        const float4* Pn = Pb + (jj + 2) * 5;
        const float4 n00 = Pn[0], n01 = Pn[1], n02 = Pn[2], n03 = Pn[3], n04 = Pn[4];
        const float4 n10 = Pn[5], n11 = Pn[6], n12 = Pn[7], n13 = Pn[8], n14 = Pn[9];

        const float s0 = sdf_eval(c00, c01, c02, c03, c04, px, py, pz);
        const float s1 = sdf_eval(c10, c11, c12, c13, c14, px, py, pz);

        const bool t0 = s0 < best;       // strict <: first-min within range
        best = t0 ? s0 : best;
        jb   = t0 ? (j0 + jj) : jb;
        const bool t1 = s1 < best;
        best = t1 ? s1 : best;
        jb   = t1 ? (j0 + jj + 1) : jb;

        c00 = n00; c01 = n01; c02 = n02; c03 = n03; c04 = n04;
        c10 = n10; c11 = n11; c12 = n12; c13 = n13; c14 = n14;
    }

    sBest[tid] = best;
    sJb[tid]   = jb;
    __syncthreads();

    // Merge halves + pass 2, threads 0..127. Lower j-half wins ties
    // (strict < on the upper half), matching jnp.argmin first-min.
    if (tid < PTS_PER_BLOCK && valid) {
        const float bl = sBest[tid];
        const float bh = sBest[tid + PTS_PER_BLOCK];
        const int   jl = sJb[tid];
        const int   jh = sJb[tid + PTS_PER_BLOCK];
        const bool hi_wins = bh < bl;
        const float bw = hi_wins ? bh : bl;
        const int   jw = hi_wins ? jh : jl;
        write_winner(params, px, py, pz, jw, bw, out_sdf, out_nrm, p);
    }
}

extern "C" void kernel_launch(void* const* d_in, const int* in_sizes, int n_in,
                              void* d_out, int out_size, void* d_ws, size_t ws_size,
                              hipStream_t stream) {
    const float* raw_scale = (const float*)d_in[0];
    const float* raw_exp   = (const float*)d_in[1];
    const float* raw_rot   = (const float*)d_in[2];
    const float* trans     = (const float*)d_in[3];
    const float* points    = (const float*)d_in[4];
    float* out = (float*)d_out;

    const int n_pts = in_sizes[4] / 3;
    float* out_sdf = out;            // [n_pts]
    float* out_nrm = out + n_pts;    // [n_pts, 3]

    float4* params = (float4*)d_ws;  // 64 * 5 * 16 B = 5120 B (+ prefetch slack)

    prep_kernel<<<1, 64, 0, stream>>>(raw_scale, raw_exp, raw_rot, trans, params);

    const int grid = (n_pts + PTS_PER_BLOCK - 1) / PTS_PER_BLOCK;
    superq_main<<<grid, 256, 0, stream>>>(params, points, out_sdf, out_nrm, n_pts);
}

// Round 9
// 88.122 us; speedup vs baseline: 1.0601x; 1.0601x over previous
//
#include <hip/hip_runtime.h>
#include <math.h>

#define N_SQ 64
#define TRUNCF 0.1f
#define EPSF 1e-6f
#define PTS_PER_BLOCK 128   // 256 thr: wave w -> j in [16w,16w+16); each lane 2 pts (packed f32)

typedef float v2f __attribute__((ext_vector_type(2)));

// --- fast hardware transcendentals (bases are guaranteed > 0 where used) ---
__device__ __forceinline__ float flog2(float x) { return __builtin_amdgcn_logf(x); }   // v_log_f32
__device__ __forceinline__ float fexp2(float x) { return __builtin_amdgcn_exp2f(x); }  // v_exp_f32
__device__ __forceinline__ float frcp(float x)  { return __builtin_amdgcn_rcpf(x); }   // v_rcp_f32
__device__ __forceinline__ float frsq(float x)  { return __builtin_amdgcn_rsqf(x); }   // v_rsq_f32

__device__ __forceinline__ v2f splat(float s) { v2f r; r.x = s; r.y = s; return r; }
__device__ __forceinline__ v2f vlog2(v2f v) { v2f r; r.x = flog2(v.x); r.y = flog2(v.y); return r; }
__device__ __forceinline__ v2f vexp2(v2f v) { v2f r; r.x = fexp2(v.x); r.y = fexp2(v.y); return r; }
__device__ __forceinline__ v2f vrsq (v2f v) { v2f r; r.x = frsq(v.x);  r.y = frsq(v.y);  return r; }
__device__ __forceinline__ v2f vmax2(v2f a, v2f b) { return __builtin_elementwise_max(a, b); }  // v_pk_max_f32
__device__ __forceinline__ v2f vmin2(v2f a, v2f b) { return __builtin_elementwise_min(a, b); }
__device__ __forceinline__ v2f vabs2(v2f a) { return __builtin_elementwise_abs(a); }

// Derived per-SQ parameter block: 5 x float4 (80 B), written to d_ws by prep_kernel.
//  [0] = R00,R01,R02,d0    d = -R^T t (translation folded into the rotate fma)
//  [1] = R10,R11,R12,d1
//  [2] = R20,R21,R22,d2
//  [3] = iSx,iSy,iSz,c2e2  (c2e2 = 2/e2)
//  [4] = c2e1, mm, nh, 0   (c2e1 = 2/e1, mm = e2/e1, nh = -e1/2)
__global__ __launch_bounds__(64) void prep_kernel(
    const float* __restrict__ raw_scale,
    const float* __restrict__ raw_exp,
    const float* __restrict__ raw_rot,
    const float* __restrict__ trans,
    float4* __restrict__ params)
{
    const int j = threadIdx.x;
    if (j >= N_SQ) return;
    float qw = raw_rot[j * 4 + 0], qx = raw_rot[j * 4 + 1];
    float qy = raw_rot[j * 4 + 2], qz = raw_rot[j * 4 + 3];
    const float qn = sqrtf(qw * qw + qx * qx + qy * qy + qz * qz);
    qw /= qn; qx /= qn; qy /= qn; qz /= qn;
    const float e1 = 1.f / (1.f + expf(-raw_exp[j * 2 + 0])) * 1.8f + 0.1f;
    const float e2 = 1.f / (1.f + expf(-raw_exp[j * 2 + 1])) * 1.8f + 0.1f;
    const float R00 = 1.f - 2.f * (qy * qy + qz * qz);
    const float R01 = 2.f * (qx * qy - qw * qz);
    const float R02 = 2.f * (qx * qz + qw * qy);
    const float R10 = 2.f * (qx * qy + qw * qz);
    const float R11 = 1.f - 2.f * (qx * qx + qz * qz);
    const float R12 = 2.f * (qy * qz - qw * qx);
    const float R20 = 2.f * (qx * qz - qw * qy);
    const float R21 = 2.f * (qy * qz + qw * qx);
    const float R22 = 1.f - 2.f * (qx * qx + qy * qy);
    const float T0 = trans[j * 3 + 0];
    const float T1 = trans[j * 3 + 1];
    const float T2 = trans[j * 3 + 2];
    const float d0 = -(R00 * T0 + R10 * T1 + R20 * T2);
    const float d1 = -(R01 * T0 + R11 * T1 + R21 * T2);
    const float d2 = -(R02 * T0 + R12 * T1 + R22 * T2);
    params[j * 5 + 0] = make_float4(R00, R01, R02, d0);
    params[j * 5 + 1] = make_float4(R10, R11, R12, d1);
    params[j * 5 + 2] = make_float4(R20, R21, R22, d2);
    params[j * 5 + 3] = make_float4(expf(-raw_scale[j * 3 + 0]),
                                    expf(-raw_scale[j * 3 + 1]),
                                    expf(-raw_scale[j * 3 + 2]),
                                    2.f / e2);
    params[j * 5 + 4] = make_float4(2.f / e1, e2 / e1, -e1 * 0.5f, 0.f);
}

// Pass-2: full gradient + normalize + store for one winning SQ (scalar).
__device__ __forceinline__ void write_winner(
    const float4* __restrict__ params,
    float px, float py, float pz, int jb, float best,
    float* __restrict__ out_sdf, float* __restrict__ out_nrm, int p)
{
    const float4 r0v = params[jb * 5 + 0];
    const float4 r1v = params[jb * 5 + 1];
    const float4 r2v = params[jb * 5 + 2];
    const float4 sc  = params[jb * 5 + 3];
    const float4 ex  = params[jb * 5 + 4];

    const float X0 = r0v.x * px + r1v.x * py + r2v.x * pz + r0v.w;
    const float X1 = r0v.y * px + r1v.y * py + r2v.y * pz + r1v.w;
    const float X2 = r0v.z * px + r1v.z * py + r2v.z * pz + r2v.w;

    const float a0 = fabsf(X0), a1 = fabsf(X1), a2 = fabsf(X2);
    const float ax = fmaxf(a0, EPSF);
    const float ay = fmaxf(a1, EPSF);
    const float az = fmaxf(a2, EPSF);
    const float sm0 = (a0 > EPSF) ? ((X0 > 0.f) ? 1.f : -1.f) : 0.f;
    const float sm1 = (a1 > EPSF) ? ((X1 > 0.f) ? 1.f : -1.f) : 0.f;
    const float sm2 = (a2 > EPSF) ? ((X2 > 0.f) ? 1.f : -1.f) : 0.f;

    const float r2 = ax * ax + ay * ay + az * az;
    const float inv_r0 = frsq(r2);
    const float r0 = r2 * inv_r0;

    const float t1 = fexp2(sc.w * flog2(ax * sc.x));
    const float t2 = fexp2(sc.w * flog2(ay * sc.y));
    const float t3 = fexp2(ex.x * flog2(az * sc.z));

    const float A = t1 + t2 + EPSF;
    const float B = fexp2(ex.y * flog2(A));
    const float S = B + t3;
    const float f = fexp2(ex.z * flog2(S));

    const float omf = 1.f - f;
    const float c1  = omf * inv_r0;
    const float w   = r0 * f * frcp(S);
    const float wBA = w * B * frcp(A);

    const float gmx = fmaf(wBA * t1, frcp(ax), c1 * ax);
    const float gmy = fmaf(wBA * t2, frcp(ay), c1 * ay);
    const float gmz = fmaf(w  * t3, frcp(az), c1 * az);
    const float gx = gmx * sm0;
    const float gy = gmy * sm1;
    const float gz = gmz * sm2;
    const float gpx = r0v.x * gx + r0v.y * gy + r0v.z * gz;
    const float gpy = r1v.x * gx + r1v.y * gy + r1v.z * gz;
    const float gpz = r2v.x * gx + r2v.y * gy + r2v.z * gz;

    const float n2 = gpx * gpx + gpy * gpy + gpz * gpz;
    const float inv_n = frsq(fmaxf(n2, 1e-24f));   // == 1/max(||g||,1e-12)

    out_sdf[p] = best;
    out_nrm[p * 3 + 0] = gpx * inv_n;
    out_nrm[p * 3 + 1] = gpy * inv_n;
    out_nrm[p * 3 + 2] = gpz * inv_n;
}

// 4-way j-split + 2 points/lane via packed f32 (v_pk_*):
//   wave w owns j in [16w, 16w+16) (readfirstlane -> scalar param loads)
//   lane l packs points base+2l, base+2l+1 into float2 components
// Regular VALU instr count per eval halves; trans stays per-component.
// Grid 2048 -> 8 blocks/CU (max occupancy preserved).
__global__ __launch_bounds__(256, 8) void superq_main(
    const float4* __restrict__ params,
    const float* __restrict__ points,
    float* __restrict__ out_sdf,
    float* __restrict__ out_nrm,
    int n_pts)
{
    __shared__ float sBest[4][PTS_PER_BLOCK];
    __shared__ int   sJb[4][PTS_PER_BLOCK];

    const int tid  = threadIdx.x;
    const int lane = tid & 63;
    const int wave = tid >> 6;
    const int base = blockIdx.x * PTS_PER_BLOCK;
    const int q0 = 2 * lane, q1 = q0 + 1;
    const int pA = base + q0;
    const int pB = base + q1;
    const bool vA = pA < n_pts;
    const bool vB = pB < n_pts;

    v2f px = splat(0.f), py = splat(0.f), pz = splat(0.f);
    if (vB) {
        // 6 consecutive floats = both points; 3x float2 loads, coalesced.
        const float2* pv = (const float2*)(points + pA * 3);
        const float2 v0 = pv[0], v1 = pv[1], v2 = pv[2];
        px.x = v0.x; py.x = v0.y; pz.x = v1.x;
        px.y = v1.y; py.y = v2.x; pz.y = v2.y;
    } else if (vA) {
        px.x = points[pA * 3 + 0];
        py.x = points[pA * 3 + 1];
        pz.x = points[pA * 3 + 2];
    }

    // Wave-uniform j base in an SGPR (R5 lesson).
    const int j0 = __builtin_amdgcn_readfirstlane(wave * (N_SQ / 4));

    v2f best = splat(INFINITY);
    int jbx = j0, jby = j0;

    #pragma unroll 2
    for (int jj = 0; jj < N_SQ / 4; ++jj) {
        const int j = j0 + jj;
        const float4 r0v = params[j * 5 + 0];
        const float4 r1v = params[j * 5 + 1];
        const float4 r2v = params[j * 5 + 2];
        const float4 sc  = params[j * 5 + 3];
        const float4 ex  = params[j * 5 + 4];

        // X = R^T p + d  (scalar-splat * v2f -> v_pk_fma_f32)
        const v2f X0 = r0v.x * px + r1v.x * py + r2v.x * pz + r0v.w;
        const v2f X1 = r0v.y * px + r1v.y * py + r2v.y * pz + r1v.w;
        const v2f X2 = r0v.z * px + r1v.z * py + r2v.z * pz + r2v.w;

        const v2f ax = vmax2(vabs2(X0), splat(EPSF));
        const v2f ay = vmax2(vabs2(X1), splat(EPSF));
        const v2f az = vmax2(vabs2(X2), splat(EPSF));

        const v2f r2 = ax * ax + ay * ay + az * az;
        const v2f inv_r0 = vrsq(r2);
        const v2f r0 = r2 * inv_r0;

        const v2f t1 = vexp2(sc.w * vlog2(ax * sc.x));
        const v2f t2 = vexp2(sc.w * vlog2(ay * sc.y));
        const v2f t3 = vexp2(ex.x * vlog2(az * sc.z));

        const v2f A = t1 + t2 + EPSF;
        const v2f B = vexp2(ex.y * vlog2(A));
        const v2f S = B + t3;
        const v2f f = vexp2(ex.z * vlog2(S));

        const v2f sdf  = r0 * (1.f - f);
        const v2f sdfc = vmin2(vmax2(sdf, splat(-TRUNCF)), splat(TRUNCF));

        // per-component strict <: first-min-wins within this wave's j range
        const bool tx = sdfc.x < best.x;
        best.x = tx ? sdfc.x : best.x;
        jbx    = tx ? j : jbx;
        const bool ty = sdfc.y < best.y;
        best.y = ty ? sdfc.y : best.y;
        jby    = ty ? j : jby;
    }

    sBest[wave][q0] = best.x;  sJb[wave][q0] = jbx;
    sBest[wave][q1] = best.y;  sJb[wave][q1] = jby;
    __syncthreads();

    // Merge in ascending wave order (strict < -> lowest j wins ties, matching
    // jnp.argmin first-min) + pass 2, threads 0..127, one point each.
    if (tid < PTS_PER_BLOCK) {
        const int p = base + tid;
        if (p < n_pts) {
            float bw = sBest[0][tid];
            int   jw = sJb[0][tid];
            #pragma unroll
            for (int w = 1; w < 4; ++w) {
                const float b  = sBest[w][tid];
                const int   jj = sJb[w][tid];
                const bool win = b < bw;
                bw = win ? b : bw;
                jw = win ? jj : jw;
            }
            const float cx = points[p * 3 + 0];   // L1/L2-hot reload
            const float cy = points[p * 3 + 1];
            const float cz = points[p * 3 + 2];
            write_winner(params, cx, cy, cz, jw, bw, out_sdf, out_nrm, p);
        }
    }
}

extern "C" void kernel_launch(void* const* d_in, const int* in_sizes, int n_in,
                              void* d_out, int out_size, void* d_ws, size_t ws_size,
                              hipStream_t stream) {
    const float* raw_scale = (const float*)d_in[0];
    const float* raw_exp   = (const float*)d_in[1];
    const float* raw_rot   = (const float*)d_in[2];
    const float* trans     = (const float*)d_in[3];
    const float* points    = (const float*)d_in[4];
    float* out = (float*)d_out;

    const int n_pts = in_sizes[4] / 3;
    float* out_sdf = out;            // [n_pts]
    float* out_nrm = out + n_pts;    // [n_pts, 3]

    float4* params = (float4*)d_ws;  // 64 * 5 * 16 B = 5120 B

    prep_kernel<<<1, 64, 0, stream>>>(raw_scale, raw_exp, raw_rot, trans, params);

    const int grid = (n_pts + PTS_PER_BLOCK - 1) / PTS_PER_BLOCK;
    superq_main<<<grid, 256, 0, stream>>>(params, points, out_sdf, out_nrm, n_pts);
}